// Round 10
// baseline (190.856 us; speedup 1.0000x reference)
//
#include <hip/hip_runtime.h>
#include <hip/hip_bf16.h>

typedef __bf16 bf16_t;
typedef __bf16 bf16x8 __attribute__((ext_vector_type(8)));
typedef _Float16 f16x4 __attribute__((ext_vector_type(4)));
typedef _Float16 f16x8 __attribute__((ext_vector_type(8)));
typedef float f32x4 __attribute__((ext_vector_type(4)));

#define SEQ    2048
#define NH     16
#define HD     64
#define HIDDEN 1024
#define LOG2E  1.44269504f
#define CSTR   41   // combine overlay stride (odd -> bank-permuting)

#if __has_builtin(__builtin_amdgcn_exp2f)
#define EXP2F(x) __builtin_amdgcn_exp2f(x)   // raw v_exp_f32: args bounded, no fixup needed
#else
#define EXP2F(x) exp2f(x)
#endif

__device__ __forceinline__ bf16_t to_bf16(float f) { return (bf16_t)f; }

// async 16B global->LDS DMA; LDS dest is wave-uniform base, HW adds lane*16.
__device__ __forceinline__ void async16(const void* g, void* l) {
    __builtin_amdgcn_global_load_lds((const __attribute__((address_space(1))) void*)g,
                                     (__attribute__((address_space(3))) void*)l, 16, 0, 0);
}

// ------ fp32 -> bf16 convert (5 segments) + mask pre-scale (x LOG2E, f32) ----
__global__ __launch_bounds__(256) void cvt_kernel(
    const float* __restrict__ s0, bf16_t* __restrict__ d0, int c0,
    const float* __restrict__ s1, bf16_t* __restrict__ d1, int c1,
    const float* __restrict__ s2, bf16_t* __restrict__ d2, int c2,
    const float* __restrict__ s3, bf16_t* __restrict__ d3, int c3,
    const float* __restrict__ s4, bf16_t* __restrict__ d4, int c4,
    const float* __restrict__ s5, float* __restrict__ d5)
{
    int blk = blockIdx.x;
    const float* s; bf16_t* d;
    if (blk < c0)              { s = s0; d = d0; }
    else if ((blk -= c0) < c1) { s = s1; d = d1; }
    else if ((blk -= c1) < c2) { s = s2; d = d2; }
    else if ((blk -= c2) < c3) { s = s3; d = d3; }
    else if ((blk -= c3) < c4) { s = s4; d = d4; }
    else {
        // mask segment: f32 -> f32 scaled by LOG2E
        blk -= c4;
        const size_t base = (size_t)blk * 2048 + threadIdx.x * 8;
        float4 a = *(const float4*)&s5[base];
        float4 b = *(const float4*)&s5[base + 4];
        a.x *= LOG2E; a.y *= LOG2E; a.z *= LOG2E; a.w *= LOG2E;
        b.x *= LOG2E; b.y *= LOG2E; b.z *= LOG2E; b.w *= LOG2E;
        *(float4*)&d5[base] = a;
        *(float4*)&d5[base + 4] = b;
        return;
    }
    const size_t base = (size_t)blk * 2048 + threadIdx.x * 8;
    const float4 a = *(const float4*)&s[base];
    const float4 b = *(const float4*)&s[base + 4];
    bf16x8 o;
    o[0] = (bf16_t)a.x; o[1] = (bf16_t)a.y; o[2] = (bf16_t)a.z; o[3] = (bf16_t)a.w;
    o[4] = (bf16_t)b.x; o[5] = (bf16_t)b.y; o[6] = (bf16_t)b.z; o[7] = (bf16_t)b.w;
    *(bf16x8*)&d[base] = o;
}

// ---------------- QKV projection: 128x128 tile, BK=32 DOUBLE-BUFFERED --------
// z=0:Q, z=1:K -> [B,S,1024] bf16; z=2:V -> [B,H,64,S] fp16 (PV B-operand),
// with s-columns PERMUTED within 32-groups so attn PV B-frag is one b128.
// LDS chunk swizzle uses ((row>>1)&3): rows are 64 B (4 chunks), so the quad
// index is 4*(row&1)+c — XOR by (row>>1)&3 makes 8 consecutive rows hit all
// 8 bank-quads (2-way = free). The old ^(row&3) left a 4-way conflict
// (rows 0,4,8,12 -> same quad; cf. m98's 1.7e7 SQ_LDS_BANK_CONFLICT).
__global__ __launch_bounds__(256, 3) void qkv_kernel(
    const bf16_t* __restrict__ X,
    const bf16_t* __restrict__ wq, const bf16_t* __restrict__ wk, const bf16_t* __restrict__ wv,
    const float* __restrict__ bq, const float* __restrict__ bk, const float* __restrict__ bv,
    bf16_t* __restrict__ qws, bf16_t* __restrict__ kws, _Float16* __restrict__ vws)
{
    // 32 KB: [buf][A 4096 | B 4096] staging; reused as 128x128 epilogue tile
    __shared__ __align__(16) bf16_t Sh[16384];
    const int z = blockIdx.z;
    const bf16_t* Wsel = (z == 0) ? wq : (z == 1) ? wk : wv;
    const float*  bsel = (z == 0) ? bq : (z == 1) ? bk : bv;
    const int m0 = blockIdx.y * 128, n0 = blockIdx.x * 128;

    const int t = threadIdx.x, lane = t & 63, w = t >> 6;
    const int w0 = w & 1, w1 = w >> 1, l15 = lane & 15, q4 = lane >> 4;

    f32x4 acc[4][4];
#pragma unroll
    for (int i = 0; i < 4; i++)
#pragma unroll
        for (int j = 0; j < 4; j++) acc[i][j] = f32x4{0.f, 0.f, 0.f, 0.f};

    auto stage = [&](int kt, int buf) {
#pragma unroll
        for (int j = 0; j < 2; j++) {
            const int s = j * 256 + t;              // 16B slot 0..511
            const int row = s >> 2, c = (s & 3) ^ ((row >> 1) & 3);
            const int lb = buf * 8192 + (j * 256 + w * 64) * 8;
            async16(&X[(size_t)(m0 + row) * HIDDEN + kt + c * 8], &Sh[lb]);
            async16(&Wsel[(size_t)(n0 + row) * HIDDEN + kt + c * 8], &Sh[lb + 4096]);
        }
    };
    stage(0, 0);

    for (int it = 0; it < 32; it++) {
        const int cur = it & 1;
        __syncthreads();                            // buf[cur] ready; buf[cur^1] free
        if (it < 31) stage((it + 1) * 32, cur ^ 1);
        const bf16_t* As = &Sh[cur * 8192];
        const bf16_t* Bs = &Sh[cur * 8192 + 4096];
        bf16x8 af[4];
#pragma unroll
        for (int ti = 0; ti < 4; ti++) {
            const int ra = w0 * 64 + ti * 16 + l15;
            af[ti] = *(const bf16x8*)&As[ra * 32 + (q4 ^ ((ra >> 1) & 3)) * 8];
        }
#pragma unroll
        for (int tj = 0; tj < 4; tj++) {
            const int rb = w1 * 64 + tj * 16 + l15;
            const bf16x8 bfr = *(const bf16x8*)&Bs[rb * 32 + (q4 ^ ((rb >> 1) & 3)) * 8];
#pragma unroll
            for (int ti = 0; ti < 4; ti++)
                acc[ti][tj] = __builtin_amdgcn_mfma_f32_16x16x32_bf16(af[ti], bfr, acc[ti][tj], 0, 0, 0);
        }
    }
    __syncthreads();

    // ---- epilogue: acc -> LDS tile (swizzled) -> coalesced b128 stores ----
    if (z < 2) {
        // LDS [m][n] bf16 128x128; chunk(8 elems) XOR-swizzled by m
#pragma unroll
        for (int tj = 0; tj < 4; tj++) {
            const int n = w1 * 64 + tj * 16 + l15;
            const float bb = bsel[n0 + n];
            const int ch = (n >> 3), sub = n & 7;
#pragma unroll
            for (int ti = 0; ti < 4; ti++)
#pragma unroll
                for (int r = 0; r < 4; r++) {
                    const int m = w0 * 64 + ti * 16 + q4 * 4 + r;
                    Sh[m * 128 + ((ch ^ (m & 15)) << 3) + sub] = to_bf16(acc[ti][tj][r] + bb);
                }
        }
        __syncthreads();
        bf16_t* dst = (z == 0) ? qws : kws;
#pragma unroll
        for (int i = 0; i < 8; i++) {
            const int g = i * 256 + t;
            const int row = g >> 4, c = g & 15;
            const bf16x8 vv = *(const bf16x8*)&Sh[row * 128 + ((c ^ (row & 15)) << 3)];
            *(bf16x8*)&dst[(size_t)(m0 + row) * HIDDEN + n0 + c * 8] = vv;
        }
    } else {
        // LDS [n(d)][m(s)] f16 128x128 (transpose in LDS)
        _Float16* Vt = (_Float16*)Sh;
#pragma unroll
        for (int tj = 0; tj < 4; tj++) {
            const int n = w1 * 64 + tj * 16 + l15;
            const float bb = bsel[n0 + n];
#pragma unroll
            for (int ti = 0; ti < 4; ti++) {
                const int mb = w0 * 64 + ti * 16 + q4 * 4;
                f16x4 v;
#pragma unroll
                for (int r = 0; r < 4; r++) v[r] = (_Float16)(acc[ti][tj][r] + bb);
                *(f16x4*)&Vt[n * 128 + (((mb >> 3) ^ (n & 15)) << 3) + (mb & 7)] = v;
            }
        }
        __syncthreads();
        const int b = m0 >> 11, sbase = m0 & (SEQ - 1);
        // permuted store: dest 16B chunk c holds true s-cols
        //   {g32*32 + (c&3)*4 + 0..3} then {+16..+19}  (g32 = c>>2)
#pragma unroll
        for (int i = 0; i < 8; i++) {
            const int g = i * 256 + t;
            const int row = g >> 4, c = g & 15;       // row = d-col, c = dest chunk
            const int sA = (c >> 2) * 32 + (c & 3) * 4;
            const int sB = sA + 16;
            const f16x4 va = *(const f16x4*)&Vt[row * 128 + (((sA >> 3) ^ (row & 15)) << 3) + (sA & 7)];
            const f16x4 vb = *(const f16x4*)&Vt[row * 128 + (((sB >> 3) ^ (row & 15)) << 3) + (sB & 7)];
            f16x8 vv;
            vv[0] = va[0]; vv[1] = va[1]; vv[2] = va[2]; vv[3] = va[3];
            vv[4] = vb[0]; vv[5] = vb[1]; vv[6] = vb[2]; vv[7] = vb[3];
            const int d = (n0 + row) & 63, hh = (n0 + row) >> 6;
            *(f16x8*)&vws[(((size_t)b * NH + hh) * HD + d) * SEQ + sbase + c * 8] = vv;
        }
    }
}

// ------- flash attention: within-tile K-split-2 x Q-split-2, x32 PV ---------
// (r7 config — best measured: 52.0 us.) grid 1024: 32 bh x 32 q-tiles(64).
// Block 256 = 4 waves (wq q-half of 32 rows, kp k-half of 32 tile rows).
// Each kf/vf LDS read feeds TWO MFMAs; 32 KB LDS -> 4 blocks/CU. Row sums
// via ones-column MFMA; kp-halves combined via odd-stride LDS overlay.
__global__ __launch_bounds__(256, 4) void attn_kernel(
    const bf16_t* __restrict__ Qw, const bf16_t* __restrict__ Kw,
    const _Float16* __restrict__ Vtw, const float* __restrict__ Msc,
    bf16_t* __restrict__ Ow)
{
    __shared__ __align__(16) bf16_t Tiles[2][2][64 * 64];   // [buf][K|V] 32 KB

    const int t = threadIdx.x, lane = t & 63, w = t >> 6;
    const int l15 = lane & 15, q4 = lane >> 4;
    const int wq = w & 1, kp = w >> 1;
    // XCD swizzle: cluster 4 heads per XCD (K/V fit per-XCD L2)
    const int lid = blockIdx.x;
    const int c8 = lid & 7, jx = lid >> 3;       // jx 0..127
    const int bh = c8 * 4 + (jx >> 5);
    const int q0 = (jx & 31) * 64;
    const int b = bh >> 4, h = bh & 15;

    const bf16_t* Qh = Qw + (size_t)b * SEQ * HIDDEN + h * HD;     // [s][1024]
    const bf16_t* Kh = Kw + (size_t)b * SEQ * HIDDEN + h * HD;
    const _Float16* Vh = Vtw + (size_t)bh * HD * SEQ;              // [64][SEQ perm]
    const float* Mrow = Msc + (size_t)b * SEQ;                     // pre-scaled

    // Q: this wave's 32 q-rows (2 q-blocks of 16)
    bf16x8 qf[2][2];
#pragma unroll
    for (int qb = 0; qb < 2; qb++)
#pragma unroll
        for (int ks = 0; ks < 2; ks++)
            qf[qb][ks] = *(const bf16x8*)&Qh[(size_t)(q0 + wq * 32 + qb * 16 + l15) * HIDDEN + ks * 32 + q4 * 8];

    f32x4 oacc[2][4];
#pragma unroll
    for (int qb = 0; qb < 2; qb++)
#pragma unroll
        for (int db = 0; db < 4; db++) oacc[qb][db] = f32x4{0.f, 0.f, 0.f, 0.f};
    f32x4 osum[2];
    osum[0] = f32x4{0.f, 0.f, 0.f, 0.f};
    osum[1] = f32x4{0.f, 0.f, 0.f, 0.f};

    // ones B-fragment for the row-sum MFMA (constant, no LDS read)
    f16x8 vone;
#pragma unroll
    for (int i = 0; i < 8; i++) vone[i] = (_Float16)1.0f;

    // ---- hoisted LDS read offsets (elem units; tile rows = 128 B) ----
    int koff[4];   // [cb*2+ks], wave's k-half rows kp*32 + cb*16 + l15
#pragma unroll
    for (int cb = 0; cb < 2; cb++)
#pragma unroll
        for (int ks = 0; ks < 2; ks++) {
            const int rk = kp * 32 + cb * 16 + l15;
            koff[cb * 2 + ks] = rk * 64 + (((ks * 4 + q4) ^ (rk & 7)) << 3);
        }
    int voff[4];   // [db], k-group = kp (pre-permuted vws layout)
#pragma unroll
    for (int db = 0; db < 4; db++) {
        const int rv = db * 16 + l15;
        voff[db] = rv * 64 + (((kp * 4 + q4) ^ (rv & 7)) << 3);
    }

    // ---- persistent staging pointers (2 slots per thread per array) ----
    const int rs0 = t >> 3, cs0 = (t & 7) ^ (rs0 & 7);
    const int rs1 = 32 + rs0, cs1 = (t & 7) ^ (rs1 & 7);
    const bf16_t*   Kp0 = Kh + (size_t)rs0 * HIDDEN + cs0 * 8;
    const bf16_t*   Kp1 = Kh + (size_t)rs1 * HIDDEN + cs1 * 8;
    const _Float16* Vp0 = Vh + (size_t)rs0 * SEQ + cs0 * 8;
    const _Float16* Vp1 = Vh + (size_t)rs1 * SEQ + cs1 * 8;
    const int db0 = (0 * 256 + w * 64) * 8, db1 = (1 * 256 + w * 64) * 8;

    auto stageKV = [&](int it, int buf) {
        const int kt = it * 64;
        bf16_t*   Kd = &Tiles[buf][0][0];
        _Float16* Vd = (_Float16*)&Tiles[buf][1][0];
        async16(Kp0 + (size_t)kt * HIDDEN, &Kd[db0]);
        async16(Vp0 + kt,                  &Vd[db0]);
        async16(Kp1 + (size_t)kt * HIDDEN, &Kd[db1]);
        async16(Vp1 + kt,                  &Vd[db1]);
    };

    auto iterBody = [&](int it, int buf) {
        __syncthreads();                       // buf loads drained; buf^1 free
        if (it < 31) stageKV(it + 1, buf ^ 1); // lands during this iter's compute

        const bf16_t*   Ksh = &Tiles[buf][0][0];
        const _Float16* Vsh = (const _Float16*)&Tiles[buf][1][0];

        // mask (pre-scaled by LOG2E) for this wave's k-half
        float4 mv4[2];
#pragma unroll
        for (int cb = 0; cb < 2; cb++)
            mv4[cb] = *(const float4*)&Mrow[it * 64 + kp * 32 + cb * 16 + q4 * 4];

        // S^T = K Q^T over wave's 32 k-rows: kf reused across both q-blocks
        f32x4 sa[2][2];
#pragma unroll
        for (int qb = 0; qb < 2; qb++)
#pragma unroll
            for (int cb = 0; cb < 2; cb++) sa[qb][cb] = f32x4{0.f, 0.f, 0.f, 0.f};
        __builtin_amdgcn_s_setprio(1);
#pragma unroll
        for (int cb = 0; cb < 2; cb++)
#pragma unroll
            for (int ks = 0; ks < 2; ks++) {
                const bf16x8 kf = *(const bf16x8*)&Ksh[koff[cb * 2 + ks]];
                sa[0][cb] = __builtin_amdgcn_mfma_f32_16x16x32_bf16(kf, qf[0][ks], sa[0][cb], 0, 0, 0);
                sa[1][cb] = __builtin_amdgcn_mfma_f32_16x16x32_bf16(kf, qf[1][ks], sa[1][cb], 0, 0, 0);
            }
        __builtin_amdgcn_s_setprio(0);

        // softmax numerator; P packed straight into x32 A-frags (slot = cb*4+r)
        f16x8 pa[2];
#pragma unroll
        for (int cb = 0; cb < 2; cb++) {
            const float4 mv = mv4[cb];
            const float mk[4] = {mv.x, mv.y, mv.z, mv.w};
#pragma unroll
            for (int qb = 0; qb < 2; qb++)
#pragma unroll
                for (int r = 0; r < 4; r++) {
                    const float p = EXP2F(fmaf(sa[qb][cb][r], 0.125f * LOG2E, mk[r]));
                    pa[qb][cb * 4 + r] = (_Float16)p;
                }
        }

        // PV: x32 f16; vf (b128) reused across both q-blocks. osum = P . 1.
        __builtin_amdgcn_s_setprio(1);
#pragma unroll
        for (int db = 0; db < 4; db++) {
            const f16x8 vf = *(const f16x8*)&Vsh[voff[db]];
            oacc[0][db] = __builtin_amdgcn_mfma_f32_16x16x32_f16(pa[0], vf, oacc[0][db], 0, 0, 0);
            oacc[1][db] = __builtin_amdgcn_mfma_f32_16x16x32_f16(pa[1], vf, oacc[1][db], 0, 0, 0);
        }
        osum[0] = __builtin_amdgcn_mfma_f32_16x16x32_f16(pa[0], vone, osum[0], 0, 0, 0);
        osum[1] = __builtin_amdgcn_mfma_f32_16x16x32_f16(pa[1], vone, osum[1], 0, 0, 0);
        __builtin_amdgcn_s_setprio(0);
    };

    stageKV(0, 0);
#pragma unroll 1
    for (int it2 = 0; it2 < 16; it2++) {   // x2 unroll: buf is compile-time
        iterBody(it2 * 2, 0);
        iterBody(it2 * 2 + 1, 1);
    }
    __syncthreads();   // compute done; Tiles reusable as combine overlay

    // ---- combine kp-halves via odd-stride overlay (rows by wq,lane) ----
    // per lane: 32 oacc f32 at (qb*4+db)*4, then 8 osum f32 at 32+qb*4
    float* Cb = (float*)&Tiles[0][0][0];
    const int crow = (wq * 64 + lane) * CSTR;   // max 127*41+39 = 5246 f32 = 21 KB
    if (kp == 1) {
#pragma unroll
        for (int qb = 0; qb < 2; qb++) {
#pragma unroll
            for (int db = 0; db < 4; db++)
                *(f32x4*)&Cb[crow + (qb * 4 + db) * 4] = oacc[qb][db];
            *(f32x4*)&Cb[crow + 32 + qb * 4] = osum[qb];
        }
    }
    __syncthreads();
    if (kp == 0) {
#pragma unroll
        for (int qb = 0; qb < 2; qb++) {
#pragma unroll
            for (int db = 0; db < 4; db++)
                oacc[qb][db] += *(const f32x4*)&Cb[crow + (qb * 4 + db) * 4];
            osum[qb] += *(const f32x4*)&Cb[crow + 32 + qb * 4];
        }
        // normalize + store: rows q = q0 + wq*32 + qb*16 + q4*4 + r; col d = db*16+l15
#pragma unroll
        for (int qb = 0; qb < 2; qb++) {
            float inv[4];
#pragma unroll
            for (int r = 0; r < 4; r++) inv[r] = 1.f / osum[qb][r];
#pragma unroll
            for (int r = 0; r < 4; r++) {
                const int srow = q0 + wq * 32 + qb * 16 + q4 * 4 + r;
#pragma unroll
                for (int db = 0; db < 4; db++)
                    Ow[((size_t)b * SEQ + srow) * HIDDEN + h * HD + db * 16 + l15] =
                        to_bf16(oacc[qb][db][r] * inv[r]);
            }
        }
    }
}

// ---------------- output projection: 64x128 tile, BK=32 dbuf, C^T frags -----
// Same ((row>>1)&3) bank-quad fix as qkv (64 B LDS rows).
__global__ __launch_bounds__(256, 2) void oproj_kernel(
    const bf16_t* __restrict__ A, const bf16_t* __restrict__ Wo,
    const float* __restrict__ bo, float* __restrict__ Out)
{
    __shared__ __align__(16) bf16_t Sh[12288];   // 24 KB: [buf][A 2048 | B 4096]
    const int m0 = blockIdx.y * 64, n0 = blockIdx.x * 128;
    const int t = threadIdx.x, lane = t & 63, w = t >> 6;
    const int l15 = lane & 15, q4 = lane >> 4;

    f32x4 acc[4][2];
#pragma unroll
    for (int i = 0; i < 4; i++)
#pragma unroll
        for (int j = 0; j < 2; j++) acc[i][j] = f32x4{0.f, 0.f, 0.f, 0.f};

    auto stage = [&](int kt, int buf) {
        {   // A: 256 slots -> 1 instr
            const int row = t >> 2, c = (t & 3) ^ ((row >> 1) & 3);
            async16(&A[(size_t)(m0 + row) * HIDDEN + kt + c * 8], &Sh[buf * 6144 + w * 64 * 8]);
        }
#pragma unroll
        for (int j = 0; j < 2; j++) {   // B: 512 slots -> 2 instrs
            const int s = j * 256 + t;
            const int row = s >> 2, c = (s & 3) ^ ((row >> 1) & 3);
            async16(&Wo[(size_t)(n0 + row) * HIDDEN + kt + c * 8],
                    &Sh[buf * 6144 + 2048 + (j * 256 + w * 64) * 8]);
        }
    };
    stage(0, 0);

    for (int it = 0; it < 32; it++) {
        const int cur = it & 1;
        __syncthreads();
        if (it < 31) stage((it + 1) * 32, cur ^ 1);
        const bf16_t* As = &Sh[cur * 6144];
        const bf16_t* Bs = &Sh[cur * 6144 + 2048];
        bf16x8 af[4];
#pragma unroll
        for (int ti = 0; ti < 4; ti++) {
            const int ra = ti * 16 + l15;
            af[ti] = *(const bf16x8*)&As[ra * 32 + (q4 ^ ((ra >> 1) & 3)) * 8];
        }
#pragma unroll
        for (int tj = 0; tj < 2; tj++) {
            const int rb = w * 32 + tj * 16 + l15;
            const bf16x8 bfr = *(const bf16x8*)&Bs[rb * 32 + (q4 ^ ((rb >> 1) & 3)) * 8];
            // swapped operands: acc holds C^T fragments (4 consecutive n per reg)
#pragma unroll
            for (int ti = 0; ti < 4; ti++)
                acc[ti][tj] = __builtin_amdgcn_mfma_f32_16x16x32_bf16(bfr, af[ti], acc[ti][tj], 0, 0, 0);
        }
    }

    // C[m = m0+ti*16+l15][n = n0+w*32+tj*16+q4*4+r] -> f32x4 stores
#pragma unroll
    for (int tj = 0; tj < 2; tj++) {
        const int nb4 = n0 + w * 32 + tj * 16 + q4 * 4;
        const float4 bb = *(const float4*)&bo[nb4];
#pragma unroll
        for (int ti = 0; ti < 4; ti++) {
            const int m = m0 + ti * 16 + l15;
            float4 ov;
            ov.x = acc[ti][tj][0] + bb.x;
            ov.y = acc[ti][tj][1] + bb.y;
            ov.z = acc[ti][tj][2] + bb.z;
            ov.w = acc[ti][tj][3] + bb.w;
            *(float4*)&Out[(size_t)m * HIDDEN + nb4] = ov;
        }
    }
}

extern "C" void kernel_launch(void* const* d_in, const int* in_sizes, int n_in,
                              void* d_out, int out_size, void* d_ws, size_t ws_size,
                              hipStream_t stream) {
    const float* X   = (const float*)d_in[0];
    const float* msk = (const float*)d_in[1];
    const float* wq  = (const float*)d_in[2];
    const float* bq  = (const float*)d_in[3];
    const float* wk  = (const float*)d_in[4];
    const float* bk  = (const float*)d_in[5];
    const float* wv  = (const float*)d_in[6];
    const float* bv  = (const float*)d_in[7];
    const float* wo  = (const float*)d_in[8];
    const float* bo  = (const float*)d_in[9];
    float* out = (float*)d_out;

    const size_t NELT = (size_t)2 * SEQ * HIDDEN;  // 4M
    const size_t WELT = (size_t)HIDDEN * HIDDEN;   // 1M
    bf16_t*    xbf = (bf16_t*)d_ws;     // [B,S,1024] bf16
    bf16_t*    qws = xbf + NELT;        // [B,S,1024] (Q)
    bf16_t*    kws = qws + NELT;        // [B,S,1024] (K)
    _Float16*  vws = (_Float16*)(kws + NELT);  // [B,H,64,S] fp16 (V^T, s-permuted)
    bf16_t*    aws = xbf;               // attn out aliases xbf (dead after qkv)
    bf16_t*    wqb = (bf16_t*)d_out;    // weight scratch in d_out (written last)
    bf16_t*    wkb = wqb + WELT;
    bf16_t*    wvb = wkb + WELT;
    bf16_t*    wob = wvb + WELT;        // 8 MB
    float*     mws = (float*)(wob + WELT);  // scaled mask 16 KB (attn-only, pre-oproj)

    cvt_kernel<<<dim3(2048 + 4 * 512 + 2), dim3(256), 0, stream>>>(
        X, xbf, 2048, wq, wqb, 512, wk, wkb, 512, wv, wvb, 512, wo, wob, 512,
        msk, mws);
    qkv_kernel<<<dim3(8, 32, 3), dim3(256), 0, stream>>>(
        xbf, wqb, wkb, wvb, bq, bk, bv, qws, kws, vws);
    attn_kernel<<<dim3(1024), dim3(256), 0, stream>>>(qws, kws, vws, mws, aws);
    oproj_kernel<<<dim3(8, 64), dim3(256), 0, stream>>>(aws, wob, bo, out);
}

// Round 12
// 185.085 us; speedup vs baseline: 1.0312x; 1.0312x over previous
//
#include <hip/hip_runtime.h>
#include <hip/hip_bf16.h>

typedef __bf16 bf16_t;
typedef __bf16 bf16x8 __attribute__((ext_vector_type(8)));
typedef _Float16 f16x4 __attribute__((ext_vector_type(4)));
typedef _Float16 f16x8 __attribute__((ext_vector_type(8)));
typedef float f32x4 __attribute__((ext_vector_type(4)));

#define SEQ    2048
#define NH     16
#define HD     64
#define HIDDEN 1024
#define LOG2E  1.44269504f
#define CSTR   41   // combine overlay stride (odd -> bank-permuting)

#if __has_builtin(__builtin_amdgcn_exp2f)
#define EXP2F(x) __builtin_amdgcn_exp2f(x)   // raw v_exp_f32: args bounded, no fixup needed
#else
#define EXP2F(x) exp2f(x)
#endif

__device__ __forceinline__ bf16_t to_bf16(float f) { return (bf16_t)f; }

// async 16B global->LDS DMA; LDS dest is wave-uniform base, HW adds lane*16.
__device__ __forceinline__ void async16(const void* g, void* l) {
    __builtin_amdgcn_global_load_lds((const __attribute__((address_space(1))) void*)g,
                                     (__attribute__((address_space(3))) void*)l, 16, 0, 0);
}

// ------ fp32 -> bf16 convert (5 segments) + mask pre-scale (x LOG2E, f32) ----
__global__ __launch_bounds__(256) void cvt_kernel(
    const float* __restrict__ s0, bf16_t* __restrict__ d0, int c0,
    const float* __restrict__ s1, bf16_t* __restrict__ d1, int c1,
    const float* __restrict__ s2, bf16_t* __restrict__ d2, int c2,
    const float* __restrict__ s3, bf16_t* __restrict__ d3, int c3,
    const float* __restrict__ s4, bf16_t* __restrict__ d4, int c4,
    const float* __restrict__ s5, float* __restrict__ d5)
{
    int blk = blockIdx.x;
    const float* s; bf16_t* d;
    if (blk < c0)              { s = s0; d = d0; }
    else if ((blk -= c0) < c1) { s = s1; d = d1; }
    else if ((blk -= c1) < c2) { s = s2; d = d2; }
    else if ((blk -= c2) < c3) { s = s3; d = d3; }
    else if ((blk -= c3) < c4) { s = s4; d = d4; }
    else {
        // mask segment: f32 -> f32 scaled by LOG2E
        blk -= c4;
        const size_t base = (size_t)blk * 2048 + threadIdx.x * 8;
        float4 a = *(const float4*)&s5[base];
        float4 b = *(const float4*)&s5[base + 4];
        a.x *= LOG2E; a.y *= LOG2E; a.z *= LOG2E; a.w *= LOG2E;
        b.x *= LOG2E; b.y *= LOG2E; b.z *= LOG2E; b.w *= LOG2E;
        *(float4*)&d5[base] = a;
        *(float4*)&d5[base + 4] = b;
        return;
    }
    const size_t base = (size_t)blk * 2048 + threadIdx.x * 8;
    const float4 a = *(const float4*)&s[base];
    const float4 b = *(const float4*)&s[base + 4];
    bf16x8 o;
    o[0] = (bf16_t)a.x; o[1] = (bf16_t)a.y; o[2] = (bf16_t)a.z; o[3] = (bf16_t)a.w;
    o[4] = (bf16_t)b.x; o[5] = (bf16_t)b.y; o[6] = (bf16_t)b.z; o[7] = (bf16_t)b.w;
    *(bf16x8*)&d[base] = o;
}

// ---------------- QKV projection: 128x128 tile, BK=32 DOUBLE-BUFFERED --------
// z=0:Q, z=1:K -> [B,S,1024] bf16; z=2:V -> [B,H,64,S] fp16 (PV B-operand),
// with s-columns PERMUTED within 32-groups so attn PV B-frag is one b128.
// LDS chunk swizzle uses ((row>>1)&3): rows are 64 B (4 chunks), so the quad
// index is 4*(row&1)+c — XOR by (row>>1)&3 makes 8 consecutive rows hit all
// 8 bank-quads (2-way = free).
__global__ __launch_bounds__(256, 3) void qkv_kernel(
    const bf16_t* __restrict__ X,
    const bf16_t* __restrict__ wq, const bf16_t* __restrict__ wk, const bf16_t* __restrict__ wv,
    const float* __restrict__ bq, const float* __restrict__ bk, const float* __restrict__ bv,
    bf16_t* __restrict__ qws, bf16_t* __restrict__ kws, _Float16* __restrict__ vws)
{
    // 32 KB: [buf][A 4096 | B 4096] staging; reused as 128x128 epilogue tile
    __shared__ __align__(16) bf16_t Sh[16384];
    const int z = blockIdx.z;
    const bf16_t* Wsel = (z == 0) ? wq : (z == 1) ? wk : wv;
    const float*  bsel = (z == 0) ? bq : (z == 1) ? bk : bv;
    const int m0 = blockIdx.y * 128, n0 = blockIdx.x * 128;

    const int t = threadIdx.x, lane = t & 63, w = t >> 6;
    const int w0 = w & 1, w1 = w >> 1, l15 = lane & 15, q4 = lane >> 4;

    f32x4 acc[4][4];
#pragma unroll
    for (int i = 0; i < 4; i++)
#pragma unroll
        for (int j = 0; j < 4; j++) acc[i][j] = f32x4{0.f, 0.f, 0.f, 0.f};

    auto stage = [&](int kt, int buf) {
#pragma unroll
        for (int j = 0; j < 2; j++) {
            const int s = j * 256 + t;              // 16B slot 0..511
            const int row = s >> 2, c = (s & 3) ^ ((row >> 1) & 3);
            const int lb = buf * 8192 + (j * 256 + w * 64) * 8;
            async16(&X[(size_t)(m0 + row) * HIDDEN + kt + c * 8], &Sh[lb]);
            async16(&Wsel[(size_t)(n0 + row) * HIDDEN + kt + c * 8], &Sh[lb + 4096]);
        }
    };
    stage(0, 0);

    for (int it = 0; it < 32; it++) {
        const int cur = it & 1;
        __syncthreads();                            // buf[cur] ready; buf[cur^1] free
        if (it < 31) stage((it + 1) * 32, cur ^ 1);
        const bf16_t* As = &Sh[cur * 8192];
        const bf16_t* Bs = &Sh[cur * 8192 + 4096];
        bf16x8 af[4];
#pragma unroll
        for (int ti = 0; ti < 4; ti++) {
            const int ra = w0 * 64 + ti * 16 + l15;
            af[ti] = *(const bf16x8*)&As[ra * 32 + (q4 ^ ((ra >> 1) & 3)) * 8];
        }
#pragma unroll
        for (int tj = 0; tj < 4; tj++) {
            const int rb = w1 * 64 + tj * 16 + l15;
            const bf16x8 bfr = *(const bf16x8*)&Bs[rb * 32 + (q4 ^ ((rb >> 1) & 3)) * 8];
#pragma unroll
            for (int ti = 0; ti < 4; ti++)
                acc[ti][tj] = __builtin_amdgcn_mfma_f32_16x16x32_bf16(af[ti], bfr, acc[ti][tj], 0, 0, 0);
        }
    }
    __syncthreads();

    // ---- epilogue: acc -> LDS tile (swizzled) -> coalesced b128 stores ----
    if (z < 2) {
        // LDS [m][n] bf16 128x128; chunk(8 elems) XOR-swizzled by m
#pragma unroll
        for (int tj = 0; tj < 4; tj++) {
            const int n = w1 * 64 + tj * 16 + l15;
            const float bb = bsel[n0 + n];
            const int ch = (n >> 3), sub = n & 7;
#pragma unroll
            for (int ti = 0; ti < 4; ti++)
#pragma unroll
                for (int r = 0; r < 4; r++) {
                    const int m = w0 * 64 + ti * 16 + q4 * 4 + r;
                    Sh[m * 128 + ((ch ^ (m & 15)) << 3) + sub] = to_bf16(acc[ti][tj][r] + bb);
                }
        }
        __syncthreads();
        bf16_t* dst = (z == 0) ? qws : kws;
#pragma unroll
        for (int i = 0; i < 8; i++) {
            const int g = i * 256 + t;
            const int row = g >> 4, c = g & 15;
            const bf16x8 vv = *(const bf16x8*)&Sh[row * 128 + ((c ^ (row & 15)) << 3)];
            *(bf16x8*)&dst[(size_t)(m0 + row) * HIDDEN + n0 + c * 8] = vv;
        }
    } else {
        // LDS [n(d)][m(s)] f16 128x128 (transpose in LDS)
        _Float16* Vt = (_Float16*)Sh;
#pragma unroll
        for (int tj = 0; tj < 4; tj++) {
            const int n = w1 * 64 + tj * 16 + l15;
            const float bb = bsel[n0 + n];
#pragma unroll
            for (int ti = 0; ti < 4; ti++) {
                const int mb = w0 * 64 + ti * 16 + q4 * 4;
                f16x4 v;
#pragma unroll
                for (int r = 0; r < 4; r++) v[r] = (_Float16)(acc[ti][tj][r] + bb);
                *(f16x4*)&Vt[n * 128 + (((mb >> 3) ^ (n & 15)) << 3) + (mb & 7)] = v;
            }
        }
        __syncthreads();
        const int b = m0 >> 11, sbase = m0 & (SEQ - 1);
        // permuted store: dest 16B chunk c holds true s-cols
        //   {g32*32 + (c&3)*4 + 0..3} then {+16..+19}  (g32 = c>>2)
#pragma unroll
        for (int i = 0; i < 8; i++) {
            const int g = i * 256 + t;
            const int row = g >> 4, c = g & 15;       // row = d-col, c = dest chunk
            const int sA = (c >> 2) * 32 + (c & 3) * 4;
            const int sB = sA + 16;
            const f16x4 va = *(const f16x4*)&Vt[row * 128 + (((sA >> 3) ^ (row & 15)) << 3) + (sA & 7)];
            const f16x4 vb = *(const f16x4*)&Vt[row * 128 + (((sB >> 3) ^ (row & 15)) << 3) + (sB & 7)];
            f16x8 vv;
            vv[0] = va[0]; vv[1] = va[1]; vv[2] = va[2]; vv[3] = va[3];
            vv[4] = vb[0]; vv[5] = vb[1]; vv[6] = vb[2]; vv[7] = vb[3];
            const int d = (n0 + row) & 63, hh = (n0 + row) >> 6;
            *(f16x8*)&vws[(((size_t)b * NH + hh) * HD + d) * SEQ + sbase + c * 8] = vv;
        }
    }
}

// ------- flash attention: within-tile K-split-2 x Q-split-2, x32 PV ---------
// (r7/r10 config — best measured: 52.0 us.) grid 1024: 32 bh x 32 q-tiles(64).
// Block 256 = 4 waves (wq q-half of 32 rows, kp k-half of 32 tile rows).
// Each kf/vf LDS read feeds TWO MFMAs; 32 KB LDS -> 4 blocks/CU. Row sums
// via ones-column MFMA; kp-halves combined via odd-stride LDS overlay.
__global__ __launch_bounds__(256, 4) void attn_kernel(
    const bf16_t* __restrict__ Qw, const bf16_t* __restrict__ Kw,
    const _Float16* __restrict__ Vtw, const float* __restrict__ Msc,
    bf16_t* __restrict__ Ow)
{
    __shared__ __align__(16) bf16_t Tiles[2][2][64 * 64];   // [buf][K|V] 32 KB

    const int t = threadIdx.x, lane = t & 63, w = t >> 6;
    const int l15 = lane & 15, q4 = lane >> 4;
    const int wq = w & 1, kp = w >> 1;
    // XCD swizzle: cluster 4 heads per XCD (K/V fit per-XCD L2)
    const int lid = blockIdx.x;
    const int c8 = lid & 7, jx = lid >> 3;       // jx 0..127
    const int bh = c8 * 4 + (jx >> 5);
    const int q0 = (jx & 31) * 64;
    const int b = bh >> 4, h = bh & 15;

    const bf16_t* Qh = Qw + (size_t)b * SEQ * HIDDEN + h * HD;     // [s][1024]
    const bf16_t* Kh = Kw + (size_t)b * SEQ * HIDDEN + h * HD;
    const _Float16* Vh = Vtw + (size_t)bh * HD * SEQ;              // [64][SEQ perm]
    const float* Mrow = Msc + (size_t)b * SEQ;                     // pre-scaled

    // Q: this wave's 32 q-rows (2 q-blocks of 16)
    bf16x8 qf[2][2];
#pragma unroll
    for (int qb = 0; qb < 2; qb++)
#pragma unroll
        for (int ks = 0; ks < 2; ks++)
            qf[qb][ks] = *(const bf16x8*)&Qh[(size_t)(q0 + wq * 32 + qb * 16 + l15) * HIDDEN + ks * 32 + q4 * 8];

    f32x4 oacc[2][4];
#pragma unroll
    for (int qb = 0; qb < 2; qb++)
#pragma unroll
        for (int db = 0; db < 4; db++) oacc[qb][db] = f32x4{0.f, 0.f, 0.f, 0.f};
    f32x4 osum[2];
    osum[0] = f32x4{0.f, 0.f, 0.f, 0.f};
    osum[1] = f32x4{0.f, 0.f, 0.f, 0.f};

    // ones B-fragment for the row-sum MFMA (constant, no LDS read)
    f16x8 vone;
#pragma unroll
    for (int i = 0; i < 8; i++) vone[i] = (_Float16)1.0f;

    // ---- hoisted LDS read offsets (elem units; tile rows = 128 B) ----
    int koff[4];   // [cb*2+ks], wave's k-half rows kp*32 + cb*16 + l15
#pragma unroll
    for (int cb = 0; cb < 2; cb++)
#pragma unroll
        for (int ks = 0; ks < 2; ks++) {
            const int rk = kp * 32 + cb * 16 + l15;
            koff[cb * 2 + ks] = rk * 64 + (((ks * 4 + q4) ^ (rk & 7)) << 3);
        }
    int voff[4];   // [db], k-group = kp (pre-permuted vws layout)
#pragma unroll
    for (int db = 0; db < 4; db++) {
        const int rv = db * 16 + l15;
        voff[db] = rv * 64 + (((kp * 4 + q4) ^ (rv & 7)) << 3);
    }

    // ---- persistent staging pointers (2 slots per thread per array) ----
    const int rs0 = t >> 3, cs0 = (t & 7) ^ (rs0 & 7);
    const int rs1 = 32 + rs0, cs1 = (t & 7) ^ (rs1 & 7);
    const bf16_t*   Kp0 = Kh + (size_t)rs0 * HIDDEN + cs0 * 8;
    const bf16_t*   Kp1 = Kh + (size_t)rs1 * HIDDEN + cs1 * 8;
    const _Float16* Vp0 = Vh + (size_t)rs0 * SEQ + cs0 * 8;
    const _Float16* Vp1 = Vh + (size_t)rs1 * SEQ + cs1 * 8;
    const int db0 = (0 * 256 + w * 64) * 8, db1 = (1 * 256 + w * 64) * 8;

    auto stageKV = [&](int it, int buf) {
        const int kt = it * 64;
        bf16_t*   Kd = &Tiles[buf][0][0];
        _Float16* Vd = (_Float16*)&Tiles[buf][1][0];
        async16(Kp0 + (size_t)kt * HIDDEN, &Kd[db0]);
        async16(Vp0 + kt,                  &Vd[db0]);
        async16(Kp1 + (size_t)kt * HIDDEN, &Kd[db1]);
        async16(Vp1 + kt,                  &Vd[db1]);
    };

    auto iterBody = [&](int it, int buf) {
        __syncthreads();                       // buf loads drained; buf^1 free
        if (it < 31) stageKV(it + 1, buf ^ 1); // lands during this iter's compute

        const bf16_t*   Ksh = &Tiles[buf][0][0];
        const _Float16* Vsh = (const _Float16*)&Tiles[buf][1][0];

        // mask (pre-scaled by LOG2E) for this wave's k-half
        float4 mv4[2];
#pragma unroll
        for (int cb = 0; cb < 2; cb++)
            mv4[cb] = *(const float4*)&Mrow[it * 64 + kp * 32 + cb * 16 + q4 * 4];

        // S^T = K Q^T over wave's 32 k-rows: kf reused across both q-blocks
        f32x4 sa[2][2];
#pragma unroll
        for (int qb = 0; qb < 2; qb++)
#pragma unroll
            for (int cb = 0; cb < 2; cb++) sa[qb][cb] = f32x4{0.f, 0.f, 0.f, 0.f};
        __builtin_amdgcn_s_setprio(1);
#pragma unroll
        for (int cb = 0; cb < 2; cb++)
#pragma unroll
            for (int ks = 0; ks < 2; ks++) {
                const bf16x8 kf = *(const bf16x8*)&Ksh[koff[cb * 2 + ks]];
                sa[0][cb] = __builtin_amdgcn_mfma_f32_16x16x32_bf16(kf, qf[0][ks], sa[0][cb], 0, 0, 0);
                sa[1][cb] = __builtin_amdgcn_mfma_f32_16x16x32_bf16(kf, qf[1][ks], sa[1][cb], 0, 0, 0);
            }
        __builtin_amdgcn_s_setprio(0);

        // softmax numerator; P packed straight into x32 A-frags (slot = cb*4+r)
        f16x8 pa[2];
#pragma unroll
        for (int cb = 0; cb < 2; cb++) {
            const float4 mv = mv4[cb];
            const float mk[4] = {mv.x, mv.y, mv.z, mv.w};
#pragma unroll
            for (int qb = 0; qb < 2; qb++)
#pragma unroll
                for (int r = 0; r < 4; r++) {
                    const float p = EXP2F(fmaf(sa[qb][cb][r], 0.125f * LOG2E, mk[r]));
                    pa[qb][cb * 4 + r] = (_Float16)p;
                }
        }

        // PV: x32 f16; vf (b128) reused across both q-blocks. osum = P . 1.
        __builtin_amdgcn_s_setprio(1);
#pragma unroll
        for (int db = 0; db < 4; db++) {
            const f16x8 vf = *(const f16x8*)&Vsh[voff[db]];
            oacc[0][db] = __builtin_amdgcn_mfma_f32_16x16x32_f16(pa[0], vf, oacc[0][db], 0, 0, 0);
            oacc[1][db] = __builtin_amdgcn_mfma_f32_16x16x32_f16(pa[1], vf, oacc[1][db], 0, 0, 0);
        }
        osum[0] = __builtin_amdgcn_mfma_f32_16x16x32_f16(pa[0], vone, osum[0], 0, 0, 0);
        osum[1] = __builtin_amdgcn_mfma_f32_16x16x32_f16(pa[1], vone, osum[1], 0, 0, 0);
        __builtin_amdgcn_s_setprio(0);
    };

    stageKV(0, 0);
#pragma unroll 1
    for (int it2 = 0; it2 < 16; it2++) {   // x2 unroll: buf is compile-time
        iterBody(it2 * 2, 0);
        iterBody(it2 * 2 + 1, 1);
    }
    __syncthreads();   // compute done; Tiles reusable as combine overlay

    // ---- combine kp-halves via odd-stride overlay (rows by wq,lane) ----
    // per lane: 32 oacc f32 at (qb*4+db)*4, then 8 osum f32 at 32+qb*4
    float* Cb = (float*)&Tiles[0][0][0];
    const int crow = (wq * 64 + lane) * CSTR;   // max 127*41+39 = 5246 f32 = 21 KB
    if (kp == 1) {
#pragma unroll
        for (int qb = 0; qb < 2; qb++) {
#pragma unroll
            for (int db = 0; db < 4; db++)
                *(f32x4*)&Cb[crow + (qb * 4 + db) * 4] = oacc[qb][db];
            *(f32x4*)&Cb[crow + 32 + qb * 4] = osum[qb];
        }
    }
    __syncthreads();
    if (kp == 0) {
#pragma unroll
        for (int qb = 0; qb < 2; qb++) {
#pragma unroll
            for (int db = 0; db < 4; db++)
                oacc[qb][db] += *(const f32x4*)&Cb[crow + (qb * 4 + db) * 4];
            osum[qb] += *(const f32x4*)&Cb[crow + 32 + qb * 4];
        }
        // normalize + store: rows q = q0 + wq*32 + qb*16 + q4*4 + r; col d = db*16+l15
#pragma unroll
        for (int qb = 0; qb < 2; qb++) {
            float inv[4];
#pragma unroll
            for (int r = 0; r < 4; r++) inv[r] = 1.f / osum[qb][r];
#pragma unroll
            for (int r = 0; r < 4; r++) {
                const int srow = q0 + wq * 32 + qb * 16 + q4 * 4 + r;
#pragma unroll
                for (int db = 0; db < 4; db++)
                    Ow[((size_t)b * SEQ + srow) * HIDDEN + h * HD + db * 16 + l15] =
                        to_bf16(oacc[qb][db][r] * inv[r]);
            }
        }
    }
}

// ---------------- output projection: 64x128 tile, BK=32 dbuf, C^T frags -----
// Same ((row>>1)&3) bank-quad fix as qkv (64 B LDS rows).
__global__ __launch_bounds__(256, 2) void oproj_kernel(
    const bf16_t* __restrict__ A, const bf16_t* __restrict__ Wo,
    const float* __restrict__ bo, float* __restrict__ Out)
{
    __shared__ __align__(16) bf16_t Sh[12288];   // 24 KB: [buf][A 2048 | B 4096]
    const int m0 = blockIdx.y * 64, n0 = blockIdx.x * 128;
    const int t = threadIdx.x, lane = t & 63, w = t >> 6;
    const int l15 = lane & 15, q4 = lane >> 4;

    f32x4 acc[4][2];
#pragma unroll
    for (int i = 0; i < 4; i++)
#pragma unroll
        for (int j = 0; j < 2; j++) acc[i][j] = f32x4{0.f, 0.f, 0.f, 0.f};

    auto stage = [&](int kt, int buf) {
        {   // A: 256 slots -> 1 instr
            const int row = t >> 2, c = (t & 3) ^ ((row >> 1) & 3);
            async16(&A[(size_t)(m0 + row) * HIDDEN + kt + c * 8], &Sh[buf * 6144 + w * 64 * 8]);
        }
#pragma unroll
        for (int j = 0; j < 2; j++) {   // B: 512 slots -> 2 instrs
            const int s = j * 256 + t;
            const int row = s >> 2, c = (s & 3) ^ ((row >> 1) & 3);
            async16(&Wo[(size_t)(n0 + row) * HIDDEN + kt + c * 8],
                    &Sh[buf * 6144 + 2048 + (j * 256 + w * 64) * 8]);
        }
    };
    stage(0, 0);

    for (int it = 0; it < 32; it++) {
        const int cur = it & 1;
        __syncthreads();
        if (it < 31) stage((it + 1) * 32, cur ^ 1);
        const bf16_t* As = &Sh[cur * 6144];
        const bf16_t* Bs = &Sh[cur * 6144 + 2048];
        bf16x8 af[4];
#pragma unroll
        for (int ti = 0; ti < 4; ti++) {
            const int ra = ti * 16 + l15;
            af[ti] = *(const bf16x8*)&As[ra * 32 + (q4 ^ ((ra >> 1) & 3)) * 8];
        }
#pragma unroll
        for (int tj = 0; tj < 2; tj++) {
            const int rb = w * 32 + tj * 16 + l15;
            const bf16x8 bfr = *(const bf16x8*)&Bs[rb * 32 + (q4 ^ ((rb >> 1) & 3)) * 8];
            // swapped operands: acc holds C^T fragments (4 consecutive n per reg)
#pragma unroll
            for (int ti = 0; ti < 4; ti++)
                acc[ti][tj] = __builtin_amdgcn_mfma_f32_16x16x32_bf16(bfr, af[ti], acc[ti][tj], 0, 0, 0);
        }
    }

    // C[m = m0+ti*16+l15][n = n0+w*32+tj*16+q4*4+r] -> f32x4 stores
#pragma unroll
    for (int tj = 0; tj < 2; tj++) {
        const int nb4 = n0 + w * 32 + tj * 16 + q4 * 4;
        const float4 bb = *(const float4*)&bo[nb4];
#pragma unroll
        for (int ti = 0; ti < 4; ti++) {
            const int m = m0 + ti * 16 + l15;
            float4 ov;
            ov.x = acc[ti][tj][0] + bb.x;
            ov.y = acc[ti][tj][1] + bb.y;
            ov.z = acc[ti][tj][2] + bb.z;
            ov.w = acc[ti][tj][3] + bb.w;
            *(float4*)&Out[(size_t)m * HIDDEN + nb4] = ov;
        }
    }
}

extern "C" void kernel_launch(void* const* d_in, const int* in_sizes, int n_in,
                              void* d_out, int out_size, void* d_ws, size_t ws_size,
                              hipStream_t stream) {
    const float* X   = (const float*)d_in[0];
    const float* msk = (const float*)d_in[1];
    const float* wq  = (const float*)d_in[2];
    const float* bq  = (const float*)d_in[3];
    const float* wk  = (const float*)d_in[4];
    const float* bk  = (const float*)d_in[5];
    const float* wv  = (const float*)d_in[6];
    const float* bv  = (const float*)d_in[7];
    const float* wo  = (const float*)d_in[8];
    const float* bo  = (const float*)d_in[9];
    float* out = (float*)d_out;

    const size_t NELT = (size_t)2 * SEQ * HIDDEN;  // 4M
    const size_t WELT = (size_t)HIDDEN * HIDDEN;   // 1M
    bf16_t*    xbf = (bf16_t*)d_ws;     // [B,S,1024] bf16
    bf16_t*    qws = xbf + NELT;        // [B,S,1024] (Q)
    bf16_t*    kws = qws + NELT;        // [B,S,1024] (K)
    _Float16*  vws = (_Float16*)(kws + NELT);  // [B,H,64,S] fp16 (V^T, s-permuted)
    bf16_t*    aws = xbf;               // attn out aliases xbf (dead after qkv)
    bf16_t*    wqb = (bf16_t*)d_out;    // weight scratch in d_out (written last)
    bf16_t*    wkb = wqb + WELT;
    bf16_t*    wvb = wkb + WELT;
    bf16_t*    wob = wvb + WELT;        // 8 MB
    float*     mws = (float*)(wob + WELT);  // scaled mask 16 KB (attn-only, pre-oproj)

    cvt_kernel<<<dim3(2048 + 4 * 512 + 2), dim3(256), 0, stream>>>(
        X, xbf, 2048, wq, wqb, 512, wk, wkb, 512, wv, wvb, 512, wo, wob, 512,
        msk, mws);
    qkv_kernel<<<dim3(8, 32, 3), dim3(256), 0, stream>>>(
        xbf, wqb, wkb, wvb, bq, bk, bv, qws, kws, vws);
    attn_kernel<<<dim3(1024), dim3(256), 0, stream>>>(qws, kws, vws, mws, aws);
    oproj_kernel<<<dim3(8, 64), dim3(256), 0, stream>>>(aws, wob, bo, out);
}